// Round 2
// baseline (307.044 us; speedup 1.0000x reference)
//
#include <hip/hip_runtime.h>

// out = A @ x, A sparse COO (rows, cols, edge_vals), x [N,64] f32.
// Strategy: counting-sort edges by destination row each call, then one wave
// per row does a serial gather+fma reduction and a single coalesced store.
// Eliminates the 80M f32 output atomics that bound round 1 (302 G atomics/s).

#define D_FEAT 64

// ---------------- fallback (round-1 kernel) ----------------
__global__ void spmv_coo_kernel(const float* __restrict__ x,
                                const int* __restrict__ rows,
                                const int* __restrict__ cols,
                                const float* __restrict__ ev,
                                float* __restrict__ out,
                                int n_edges) {
    const int lane = threadIdx.x & 63;
    const int wave_in_block = threadIdx.x >> 6;
    const int waves_per_block = blockDim.x >> 6;
    const int wave_global = blockIdx.x * waves_per_block + wave_in_block;
    const int n_waves = gridDim.x * waves_per_block;
    for (int e = wave_global; e < n_edges; e += n_waves) {
        const int r = rows[e];
        const int c = cols[e];
        const float v = ev[e];
        atomicAdd(&out[r * D_FEAT + lane], v * x[c * D_FEAT + lane]);
    }
}

// ---------------- phase 1: histogram ----------------
__global__ void hist_kernel(const int* __restrict__ rows, int* __restrict__ counts,
                            int n_edges) {
    int gid = blockIdx.x * blockDim.x + threadIdx.x;
    int stride = gridDim.x * blockDim.x;
    for (int e = gid; e < n_edges; e += stride)
        atomicAdd(&counts[rows[e]], 1);
}

// ---------------- phase 2: scan (3 kernels) ----------------
// 2a: per-256-block exclusive scan, block totals out.
__global__ void scan_block_kernel(const int* __restrict__ counts,
                                  int* __restrict__ offsets,
                                  int* __restrict__ blocksums, int n) {
    __shared__ int s[256];
    int t = threadIdx.x;
    int gid = blockIdx.x * 256 + t;
    int val = (gid < n) ? counts[gid] : 0;
    s[t] = val;
    __syncthreads();
    for (int off = 1; off < 256; off <<= 1) {
        int tmp = (t >= off) ? s[t - off] : 0;
        __syncthreads();
        s[t] += tmp;
        __syncthreads();
    }
    if (gid < n) offsets[gid] = s[t] - val;   // exclusive within block
    if (t == 0) blocksums[blockIdx.x] = s[255];
}

// 2b: serial scan of block sums (NBLK ~ 391, one thread is fine).
__global__ void scan_tops_kernel(int* __restrict__ blocksums, int nblk) {
    if (threadIdx.x == 0 && blockIdx.x == 0) {
        int running = 0;
        for (int b = 0; b < nblk; ++b) {
            int t = blocksums[b];
            blocksums[b] = running;
            running += t;
        }
    }
}

// 2c: add block prefix; copy to cursor; write offsets[n] = E.
__global__ void scan_add_kernel(int* __restrict__ offsets,
                                const int* __restrict__ blocksums,
                                int* __restrict__ cursor, int n, int n_edges) {
    int gid = blockIdx.x * 256 + threadIdx.x;
    if (gid < n) {
        int v = offsets[gid] + blocksums[gid >> 8];
        offsets[gid] = v;
        cursor[gid] = v;
    }
    if (gid == 0) offsets[n] = n_edges;
}

// ---------------- phase 3: scatter into row-sorted order ----------------
__global__ void scatter_kernel(const int* __restrict__ rows,
                               const int* __restrict__ cols,
                               const float* __restrict__ ev,
                               int* __restrict__ cursor,
                               uint2* __restrict__ pairs, int n_edges) {
    int gid = blockIdx.x * blockDim.x + threadIdx.x;
    int stride = gridDim.x * blockDim.x;
    for (int e = gid; e < n_edges; e += stride) {
        int r = rows[e];
        int pos = atomicAdd(&cursor[r], 1);
        uint2 p;
        p.x = (unsigned)cols[e];
        p.y = __float_as_uint(ev[e]);
        pairs[pos] = p;
    }
}

// ---------------- phase 4: per-row wave reduction ----------------
__global__ void reduce_kernel(const float* __restrict__ x,
                              const int* __restrict__ offsets,
                              const uint2* __restrict__ pairs,
                              float* __restrict__ out, int n_rows) {
    const int lane = threadIdx.x & 63;
    const int wave = blockIdx.x * (blockDim.x >> 6) + (threadIdx.x >> 6);
    if (wave >= n_rows) return;
    const int s = offsets[wave];
    const int e = offsets[wave + 1];
    float acc = 0.0f;
    for (int i = s; i < e; ++i) {
        uint2 p = pairs[i];                       // broadcast 8B load
        acc += __uint_as_float(p.y) * x[(int)p.x * D_FEAT + lane];  // coalesced gather
    }
    out[wave * D_FEAT + lane] = acc;              // coalesced store, covers all rows
}

extern "C" void kernel_launch(void* const* d_in, const int* in_sizes, int n_in,
                              void* d_out, int out_size, void* d_ws, size_t ws_size,
                              hipStream_t stream) {
    const float* x    = (const float*)d_in[1];
    const int*   rows = (const int*)d_in[2];
    const int*   cols = (const int*)d_in[3];
    const float* ev   = (const float*)d_in[4];
    float* out = (float*)d_out;
    const int n_edges = in_sizes[3];
    const int n_rows  = out_size / D_FEAT;

    // workspace layout (bytes)
    size_t off_counts  = 0;
    size_t off_offsets = off_counts + (size_t)n_rows * 4;
    size_t off_cursor  = off_offsets + ((size_t)n_rows + 2) * 4;   // n+1 ints, pad
    const int nblk = (n_rows + 255) / 256;
    size_t off_bsums   = off_cursor + (size_t)n_rows * 4;
    size_t off_pairs   = (off_bsums + (size_t)nblk * 4 + 7) & ~(size_t)7;
    size_t need = off_pairs + (size_t)n_edges * 8;

    if (ws_size < need) {
        // fallback: atomic version
        hipMemsetAsync(d_out, 0, (size_t)out_size * sizeof(float), stream);
        spmv_coo_kernel<<<4096, 256, 0, stream>>>(x, rows, cols, ev, out, n_edges);
        return;
    }

    char* ws = (char*)d_ws;
    int*   counts  = (int*)(ws + off_counts);
    int*   offsets = (int*)(ws + off_offsets);
    int*   cursor  = (int*)(ws + off_cursor);
    int*   bsums   = (int*)(ws + off_bsums);
    uint2* pairs   = (uint2*)(ws + off_pairs);

    hipMemsetAsync(counts, 0, (size_t)n_rows * 4, stream);

    const int block = 256;
    const int gs_grid = 2048;   // grid-stride for E-sized kernels

    hist_kernel<<<gs_grid, block, 0, stream>>>(rows, counts, n_edges);
    scan_block_kernel<<<nblk, 256, 0, stream>>>(counts, offsets, bsums, n_rows);
    scan_tops_kernel<<<1, 64, 0, stream>>>(bsums, nblk);
    scan_add_kernel<<<nblk, 256, 0, stream>>>(offsets, bsums, cursor, n_rows, n_edges);
    scatter_kernel<<<gs_grid, block, 0, stream>>>(rows, cols, ev, cursor, pairs, n_edges);

    const int waves_per_block = block / 64;
    const int rgrid = (n_rows + waves_per_block - 1) / waves_per_block;
    reduce_kernel<<<rgrid, block, 0, stream>>>(x, offsets, pairs, out, n_rows);
}

// Round 3
// 211.561 us; speedup vs baseline: 1.4513x; 1.4513x over previous
//
#include <hip/hip_runtime.h>

// out = A @ x, A sparse COO (rows, cols, edge_vals), x [N,64] f32.
// Counting-sort edges by destination row, then one wave per row:
// coalesced pair load + shfl broadcast + unrolled gather/fma + single store.

#define D_FEAT 64

// ---------------- fallback (round-1 kernel) ----------------
__global__ void spmv_coo_kernel(const float* __restrict__ x,
                                const int* __restrict__ rows,
                                const int* __restrict__ cols,
                                const float* __restrict__ ev,
                                float* __restrict__ out,
                                int n_edges) {
    const int lane = threadIdx.x & 63;
    const int wave_global = blockIdx.x * (blockDim.x >> 6) + (threadIdx.x >> 6);
    const int n_waves = gridDim.x * (blockDim.x >> 6);
    for (int e = wave_global; e < n_edges; e += n_waves) {
        atomicAdd(&out[rows[e] * D_FEAT + lane], ev[e] * x[cols[e] * D_FEAT + lane]);
    }
}

// ---------------- phase 1: histogram ----------------
__global__ void hist_kernel(const int* __restrict__ rows, int* __restrict__ counts,
                            int n_edges) {
    int gid = blockIdx.x * blockDim.x + threadIdx.x;
    int stride = gridDim.x * blockDim.x;
    for (int e = gid; e < n_edges; e += stride)
        atomicAdd(&counts[rows[e]], 1);
}

// ---------------- phase 2: scan ----------------
// 2a: per-256-block exclusive scan, block totals out.
__global__ void scan_block_kernel(const int* __restrict__ counts,
                                  int* __restrict__ offsets,
                                  int* __restrict__ blocksums, int n) {
    __shared__ int s[256];
    int t = threadIdx.x;
    int gid = blockIdx.x * 256 + t;
    int val = (gid < n) ? counts[gid] : 0;
    s[t] = val;
    __syncthreads();
    for (int off = 1; off < 256; off <<= 1) {
        int tmp = (t >= off) ? s[t - off] : 0;
        __syncthreads();
        s[t] += tmp;
        __syncthreads();
    }
    if (gid < n) offsets[gid] = s[t] - val;   // exclusive within block
    if (t == 0) blocksums[blockIdx.x] = s[255];
}

// 2b: parallel single-block scan of block sums (nblk <= 512).
__global__ void scan_tops_kernel(int* __restrict__ blocksums, int nblk) {
    __shared__ int s[512];
    int t = threadIdx.x;
    int val = (t < nblk) ? blocksums[t] : 0;
    s[t] = val;
    __syncthreads();
    for (int off = 1; off < 512; off <<= 1) {
        int tmp = (t >= off) ? s[t - off] : 0;
        __syncthreads();
        s[t] += tmp;
        __syncthreads();
    }
    if (t < nblk) blocksums[t] = s[t] - val;  // exclusive
}

// 2c: add block prefix; copy to cursor; write offsets[n] = E.
__global__ void scan_add_kernel(int* __restrict__ offsets,
                                const int* __restrict__ blocksums,
                                int* __restrict__ cursor, int n, int n_edges) {
    int gid = blockIdx.x * 256 + threadIdx.x;
    if (gid < n) {
        int v = offsets[gid] + blocksums[gid >> 8];
        offsets[gid] = v;
        cursor[gid] = v;
    }
    if (gid == 0) offsets[n] = n_edges;
}

// ---------------- phase 3: scatter into row-sorted order ----------------
__global__ void scatter_kernel(const int* __restrict__ rows,
                               const int* __restrict__ cols,
                               const float* __restrict__ ev,
                               int* __restrict__ cursor,
                               uint2* __restrict__ pairs, int n_edges) {
    int gid = blockIdx.x * blockDim.x + threadIdx.x;
    int stride = gridDim.x * blockDim.x;
    for (int e = gid; e < n_edges; e += stride) {
        int r = rows[e];
        int pos = atomicAdd(&cursor[r], 1);
        uint2 p;
        p.x = (unsigned)cols[e];
        p.y = __float_as_uint(ev[e]);
        pairs[pos] = p;
    }
}

// ---------------- phase 4: per-row wave reduction ----------------
// One wave per row. Coalesced vector load of up to 64 pairs, shfl broadcast,
// 2-way unrolled gather+fma (keeps >=2 gathers in flight per wave).
__global__ void __launch_bounds__(256) reduce_kernel(
        const float* __restrict__ x,
        const int* __restrict__ offsets,
        const uint2* __restrict__ pairs,
        float* __restrict__ out, int n_rows) {
    const int lane = threadIdx.x & 63;
    const int wave = blockIdx.x * (blockDim.x >> 6) + (threadIdx.x >> 6);
    if (wave >= n_rows) return;
    const int s = offsets[wave];
    const int e = offsets[wave + 1];
    float acc0 = 0.0f, acc1 = 0.0f;
    for (int base = s; base < e; base += 64) {
        const int cnt = min(64, e - base);
        int   pc = 0;
        float pv = 0.0f;
        if (lane < cnt) {
            uint2 p = pairs[base + lane];   // one coalesced load for whole row
            pc = (int)p.x;
            pv = __uint_as_float(p.y);
        }
        int j = 0;
        for (; j + 2 <= cnt; j += 2) {
            int   c0 = __shfl(pc, j);
            float v0 = __shfl(pv, j);
            int   c1 = __shfl(pc, j + 1);
            float v1 = __shfl(pv, j + 1);
            acc0 += v0 * x[c0 * D_FEAT + lane];
            acc1 += v1 * x[c1 * D_FEAT + lane];
        }
        if (j < cnt) {
            int   c0 = __shfl(pc, j);
            float v0 = __shfl(pv, j);
            acc0 += v0 * x[c0 * D_FEAT + lane];
        }
    }
    out[wave * D_FEAT + lane] = acc0 + acc1;
}

extern "C" void kernel_launch(void* const* d_in, const int* in_sizes, int n_in,
                              void* d_out, int out_size, void* d_ws, size_t ws_size,
                              hipStream_t stream) {
    const float* x    = (const float*)d_in[1];
    const int*   rows = (const int*)d_in[2];
    const int*   cols = (const int*)d_in[3];
    const float* ev   = (const float*)d_in[4];
    float* out = (float*)d_out;
    const int n_edges = in_sizes[3];
    const int n_rows  = out_size / D_FEAT;

    // workspace layout (bytes)
    size_t off_counts  = 0;
    size_t off_offsets = off_counts + (size_t)n_rows * 4;
    size_t off_cursor  = off_offsets + ((size_t)n_rows + 2) * 4;
    const int nblk = (n_rows + 255) / 256;          // 391 for N=100K (<=512)
    size_t off_bsums   = off_cursor + (size_t)n_rows * 4;
    size_t off_pairs   = (off_bsums + (size_t)nblk * 4 + 7) & ~(size_t)7;
    size_t need = off_pairs + (size_t)n_edges * 8;

    if (ws_size < need || nblk > 512) {
        hipMemsetAsync(d_out, 0, (size_t)out_size * sizeof(float), stream);
        spmv_coo_kernel<<<4096, 256, 0, stream>>>(x, rows, cols, ev, out, n_edges);
        return;
    }

    char* ws = (char*)d_ws;
    int*   counts  = (int*)(ws + off_counts);
    int*   offsets = (int*)(ws + off_offsets);
    int*   cursor  = (int*)(ws + off_cursor);
    int*   bsums   = (int*)(ws + off_bsums);
    uint2* pairs   = (uint2*)(ws + off_pairs);

    hipMemsetAsync(counts, 0, (size_t)n_rows * 4, stream);

    const int block = 256;
    const int gs_grid = 2048;

    hist_kernel<<<gs_grid, block, 0, stream>>>(rows, counts, n_edges);
    scan_block_kernel<<<nblk, 256, 0, stream>>>(counts, offsets, bsums, n_rows);
    scan_tops_kernel<<<1, 512, 0, stream>>>(bsums, nblk);
    scan_add_kernel<<<nblk, 256, 0, stream>>>(offsets, bsums, cursor, n_rows, n_edges);
    scatter_kernel<<<gs_grid, block, 0, stream>>>(rows, cols, ev, cursor, pairs, n_edges);

    const int waves_per_block = block / 64;
    const int rgrid = (n_rows + waves_per_block - 1) / waves_per_block;
    reduce_kernel<<<rgrid, block, 0, stream>>>(x, offsets, pairs, out, n_rows);
}